// Round 1
// baseline (503.796 us; speedup 1.0000x reference)
//
#include <hip/hip_runtime.h>

// LatentPyramid: quant-noise + transpose grids to [H,W,C] in ws, then fused
// per-point gather (4-corner concat from high-res, bilinear-zeropad from
// low-res). Output [N, 68] fp32.

#define QSTEP 0.0625f  // 1/16

constexpr int N_PTS = 2097152;
constexpr int C0 = 12, RES0 = 1024;
constexpr int C1 = 20, RES1 = 512;
constexpr int OUT_C = 4 * C0 + C1;  // 68

// ---------------- pre-pass: fuse noise, transpose [C,H,W] -> [H,W,C] ------

__global__ void __launch_bounds__(256)
prep0(const float* __restrict__ g, const float* __restrict__ nz,
      float* __restrict__ ws) {
    int idx = blockIdx.x * blockDim.x + threadIdx.x;  // texel id, < RES0*RES0
    const int HW = RES0 * RES0;
    float v[C0];
#pragma unroll
    for (int c = 0; c < C0; ++c)
        v[c] = g[(size_t)c * HW + idx] + (nz[(size_t)c * HW + idx] - 0.5f) * QSTEP;
    float4* dst = (float4*)(ws + (size_t)idx * C0);
    dst[0] = make_float4(v[0], v[1], v[2], v[3]);
    dst[1] = make_float4(v[4], v[5], v[6], v[7]);
    dst[2] = make_float4(v[8], v[9], v[10], v[11]);
}

__global__ void __launch_bounds__(256)
prep1(const float* __restrict__ g, const float* __restrict__ nz,
      float* __restrict__ ws) {
    int idx = blockIdx.x * blockDim.x + threadIdx.x;  // texel id, < RES1*RES1
    const int HW = RES1 * RES1;
    float v[C1];
#pragma unroll
    for (int c = 0; c < C1; ++c)
        v[c] = g[(size_t)c * HW + idx] + (nz[(size_t)c * HW + idx] - 0.5f) * QSTEP;
    float4* dst = (float4*)(ws + (size_t)idx * C1);
#pragma unroll
    for (int i = 0; i < 5; ++i)
        dst[i] = make_float4(v[4 * i], v[4 * i + 1], v[4 * i + 2], v[4 * i + 3]);
}

// ---------------- main gather: thread per point ---------------------------

__global__ void __launch_bounds__(256)
gather_fast(const float* __restrict__ uv, const float* __restrict__ ws0,
            const float* __restrict__ ws1, float* __restrict__ out) {
    int n = blockIdx.x * blockDim.x + threadIdx.x;
    if (n >= N_PTS) return;
    float2 p = ((const float2*)uv)[n];

    float4* o = (float4*)(out + (size_t)n * OUT_C);

    // ---- high-res: 4-corner raw gather (clamped), 12 ch each ----
    {
        float px = p.x * (float)RES0 - 0.5f;
        float py = p.y * (float)RES0 - 0.5f;
        int x0 = (int)floorf(px);
        int y0 = (int)floorf(py);
        x0 = min(max(x0, 0), RES0 - 2);
        y0 = min(max(y0, 0), RES0 - 2);
        const float4* t00 = (const float4*)(ws0 + ((size_t)y0 * RES0 + x0) * C0);
        const float4* t01 = (const float4*)(ws0 + ((size_t)y0 * RES0 + x0 + 1) * C0);
        const float4* t10 = (const float4*)(ws0 + ((size_t)(y0 + 1) * RES0 + x0) * C0);
        const float4* t11 = (const float4*)(ws0 + ((size_t)(y0 + 1) * RES0 + x0 + 1) * C0);
        o[0] = t00[0]; o[1] = t00[1]; o[2] = t00[2];
        o[3] = t01[0]; o[4] = t01[1]; o[5] = t01[2];
        o[6] = t10[0]; o[7] = t10[1]; o[8] = t10[2];
        o[9] = t11[0]; o[10] = t11[1]; o[11] = t11[2];
    }

    // ---- low-res: bilinear with zero padding, 20 ch ----
    {
        float qx = p.x * (float)RES1 - 0.5f;
        float qy = p.y * (float)RES1 - 0.5f;
        float fx = floorf(qx), fy = floorf(qy);
        float wx = qx - fx, wy = qy - fy;
        int ix0 = (int)fx, iy0 = (int)fy;

        float acc[C1];
#pragma unroll
        for (int c = 0; c < C1; ++c) acc[c] = 0.f;

        auto tap = [&](int iy, int ix, float w) {
            if (ix < 0 || ix >= RES1 || iy < 0 || iy >= RES1) return;
            const float4* t = (const float4*)(ws1 + ((size_t)iy * RES1 + ix) * C1);
#pragma unroll
            for (int i = 0; i < 5; ++i) {
                float4 v = t[i];
                acc[4 * i + 0] += w * v.x;
                acc[4 * i + 1] += w * v.y;
                acc[4 * i + 2] += w * v.z;
                acc[4 * i + 3] += w * v.w;
            }
        };
        tap(iy0,     ix0,     (1.f - wy) * (1.f - wx));
        tap(iy0,     ix0 + 1, (1.f - wy) * wx);
        tap(iy0 + 1, ix0,     wy * (1.f - wx));
        tap(iy0 + 1, ix0 + 1, wy * wx);

#pragma unroll
        for (int i = 0; i < 5; ++i)
            o[12 + i] = make_float4(acc[4 * i], acc[4 * i + 1],
                                    acc[4 * i + 2], acc[4 * i + 3]);
    }
}

// ---------------- fallback: direct gather from [C,H,W] (if ws too small) --

__global__ void __launch_bounds__(256)
gather_direct(const float* __restrict__ uv, const float* __restrict__ g0,
              const float* __restrict__ n0, const float* __restrict__ g1,
              const float* __restrict__ n1, float* __restrict__ out) {
    int n = blockIdx.x * blockDim.x + threadIdx.x;
    if (n >= N_PTS) return;
    float2 p = ((const float2*)uv)[n];
    float* o = out + (size_t)n * OUT_C;

    {
        const int HW = RES0 * RES0;
        float px = p.x * (float)RES0 - 0.5f;
        float py = p.y * (float)RES0 - 0.5f;
        int x0 = (int)floorf(px);
        int y0 = (int)floorf(py);
        x0 = min(max(x0, 0), RES0 - 2);
        y0 = min(max(y0, 0), RES0 - 2);
        int base[4] = {y0 * RES0 + x0, y0 * RES0 + x0 + 1,
                       (y0 + 1) * RES0 + x0, (y0 + 1) * RES0 + x0 + 1};
#pragma unroll
        for (int t = 0; t < 4; ++t)
#pragma unroll
            for (int c = 0; c < C0; ++c) {
                size_t off = (size_t)c * HW + base[t];
                o[t * C0 + c] = g0[off] + (n0[off] - 0.5f) * QSTEP;
            }
    }
    {
        const int HW = RES1 * RES1;
        float qx = p.x * (float)RES1 - 0.5f;
        float qy = p.y * (float)RES1 - 0.5f;
        float fx = floorf(qx), fy = floorf(qy);
        float wx = qx - fx, wy = qy - fy;
        int ix0 = (int)fx, iy0 = (int)fy;
        float acc[C1];
#pragma unroll
        for (int c = 0; c < C1; ++c) acc[c] = 0.f;
        int ixs[4] = {ix0, ix0 + 1, ix0, ix0 + 1};
        int iys[4] = {iy0, iy0, iy0 + 1, iy0 + 1};
        float w4[4] = {(1.f - wy) * (1.f - wx), (1.f - wy) * wx,
                       wy * (1.f - wx), wy * wx};
#pragma unroll
        for (int t = 0; t < 4; ++t) {
            int ix = ixs[t], iy = iys[t];
            if (ix < 0 || ix >= RES1 || iy < 0 || iy >= RES1) continue;
            float w = w4[t];
#pragma unroll
            for (int c = 0; c < C1; ++c) {
                size_t off = (size_t)c * HW + iy * RES1 + ix;
                acc[c] += w * (g1[off] + (n1[off] - 0.5f) * QSTEP);
            }
        }
#pragma unroll
        for (int c = 0; c < C1; ++c) o[4 * C0 + c] = acc[c];
    }
}

extern "C" void kernel_launch(void* const* d_in, const int* in_sizes, int n_in,
                              void* d_out, int out_size, void* d_ws, size_t ws_size,
                              hipStream_t stream) {
    const float* uv = (const float*)d_in[0];
    const float* g0 = (const float*)d_in[1];
    const float* g1 = (const float*)d_in[2];
    const float* n0 = (const float*)d_in[3];
    const float* n1 = (const float*)d_in[4];
    float* out = (float*)d_out;

    const size_t ws0_elems = (size_t)RES0 * RES0 * C0;  // 12 M floats
    const size_t ws1_elems = (size_t)RES1 * RES1 * C1;  // 5 M floats
    const size_t need = (ws0_elems + ws1_elems) * sizeof(float);  // 68 MiB

    if (ws_size >= need) {
        float* ws0 = (float*)d_ws;
        float* ws1 = ws0 + ws0_elems;
        prep0<<<RES0 * RES0 / 256, 256, 0, stream>>>(g0, n0, ws0);
        prep1<<<RES1 * RES1 / 256, 256, 0, stream>>>(g1, n1, ws1);
        gather_fast<<<N_PTS / 256, 256, 0, stream>>>(uv, ws0, ws1, out);
    } else {
        gather_direct<<<N_PTS / 256, 256, 0, stream>>>(uv, g0, n0, g1, n1, out);
    }
}